// Round 1
// baseline (629.433 us; speedup 1.0000x reference)
//
#include <hip/hip_runtime.h>
#include <hip/hip_bf16.h>

#define BGR   128
#define NPER  1024
#define NK    7
#define NNODES (BGR*NPER)

typedef __attribute__((ext_vector_type(8))) short short8;
typedef __attribute__((ext_vector_type(8))) unsigned short ushort8;
typedef __attribute__((ext_vector_type(4))) float floatx4;

static __device__ __forceinline__ float bf2f(unsigned short u) {
    unsigned int x = ((unsigned int)u) << 16;
    return __builtin_bit_cast(float, x);
}
static __device__ __forceinline__ unsigned short f2bf(float f) {
    unsigned int x = __builtin_bit_cast(unsigned int, f);
    unsigned int lsb = (x >> 16) & 1u;
    x += 0x7fffu + lsb;
    return (unsigned short)(x >> 16);
}

// ---------------- 0: repack pos into float4 for uniform 16B loads ----------------
__global__ __launch_bounds__(256) void repack_pos_kernel(const float* __restrict__ pos,
                                                         floatx4* __restrict__ p4) {
    int i = blockIdx.x * blockDim.x + threadIdx.x;
    if (i < NNODES) {
        floatx4 v;
        v.x = pos[(size_t)i*3+0]; v.y = pos[(size_t)i*3+1]; v.z = pos[(size_t)i*3+2]; v.w = 0.f;
        p4[i] = v;
    }
}

// ---------------- 1: per-graph brute-force kNN (top-7 smallest d^2) ----------------
__global__ __launch_bounds__(512) void knn_kernel(const floatx4* __restrict__ p4,
                                                  int* __restrict__ idx) {
    int g = blockIdx.x >> 1;
    int i_local = ((blockIdx.x & 1) << 9) + threadIdx.x;
    int base = g * NPER;
    const floatx4* pg = p4 + base;
    floatx4 me = pg[i_local];
    float b0=3e38f,b1=3e38f,b2=3e38f,b3=3e38f,b4=3e38f,b5=3e38f,b6=3e38f;
    int   i0=0,i1=0,i2=0,i3=0,i4=0,i5=0,i6=0;
    for (int j = 0; j < NPER; ++j) {
        floatx4 q = pg[j];                       // wave-uniform -> scalar/broadcast load
        float dx = me.x-q.x, dy = me.y-q.y, dz = me.z-q.z;
        float d = dx*dx + dy*dy + dz*dz;
        d = (j == i_local) ? 3e38f : d;          // no self loops
        if (d < b6) {
            float t = d; int ti = j;
            #define BUB(bb,ii) { bool c = t < bb; float tf = bb; int tii = ii; \
                                 bb = c ? t : bb; ii = c ? ti : ii; t = c ? tf : t; ti = c ? tii : ti; }
            BUB(b0,i0) BUB(b1,i1) BUB(b2,i2) BUB(b3,i3) BUB(b4,i4) BUB(b5,i5) BUB(b6,i6)
            #undef BUB
        }
    }
    int* op = idx + (size_t)(base + i_local) * NK;
    op[0]=base+i0; op[1]=base+i1; op[2]=base+i2; op[3]=base+i3;
    op[4]=base+i4; op[5]=base+i5; op[6]=base+i6;
}

// ---------------- 2: feat1 — x(16) -> kf/qf/vf/sk (64) with W in registers ----------------
__global__ __launch_bounds__(256) void feat1_kernel(
    const float* __restrict__ x,
    const float* __restrict__ wk, const float* __restrict__ bk,
    const float* __restrict__ wq, const float* __restrict__ bq,
    const float* __restrict__ wv, const float* __restrict__ bv,
    const float* __restrict__ wsm, const float* __restrict__ bs,
    unsigned short* __restrict__ kf, unsigned short* __restrict__ qf,
    unsigned short* __restrict__ vf, unsigned short* __restrict__ sk) {
    int c = threadIdx.x & 63;
    float Wk[16], Wq[16], Wv[16], Ws[16];
    #pragma unroll
    for (int k = 0; k < 16; ++k) {
        Wk[k] = wk[k*64+c]; Wq[k] = wq[k*64+c]; Wv[k] = wv[k*64+c]; Ws[k] = wsm[k*64+c];
    }
    float Bk = bk[c], Bq = bq[c], Bv = bv[c], Bs = bs[c];
    int wave = blockIdx.x * (blockDim.x >> 6) + (threadIdx.x >> 6);
    int nw   = gridDim.x * (blockDim.x >> 6);
    for (int n = wave; n < NNODES; n += nw) {
        const float* xr = x + (size_t)n * 16;
        float ak = Bk, aq = Bq, av = Bv, as = Bs;
        #pragma unroll
        for (int k = 0; k < 16; ++k) {
            float xv = xr[k];
            ak += xv * Wk[k]; aq += xv * Wq[k]; av += xv * Wv[k]; as += xv * Ws[k];
        }
        size_t o = (size_t)n * 64 + c;
        kf[o] = f2bf(ak); qf[o] = f2bf(aq); vf[o] = f2bf(av); sk[o] = f2bf(as);
    }
}

// ---------------- 3: gated conv, C channels (lanes = channels, no atomics) ----------------
template<int C>
__global__ __launch_bounds__(256) void conv_kernel(
    const unsigned short* __restrict__ kf, const unsigned short* __restrict__ qf,
    const unsigned short* __restrict__ vf, const unsigned short* __restrict__ sk,
    const int* __restrict__ idx, unsigned short* __restrict__ h) {
    int c, slot, ns;
    if (C == 64) {
        c = threadIdx.x & 63;
        slot = blockIdx.x * 4 + (threadIdx.x >> 6);
        ns = gridDim.x * 4;
    } else {
        c = threadIdx.x & 127;
        slot = blockIdx.x * 2 + (threadIdx.x >> 7);
        ns = gridDim.x * 2;
    }
    for (int n = slot; n < NNODES; n += ns) {
        const int* nb = idx + (size_t)n * NK;
        size_t o = (size_t)n * C + c;
        float kv  = bf2f(kf[o]);
        float acc = bf2f(sk[o]);
        #pragma unroll
        for (int k = 0; k < NK; ++k) {
            int j = nb[k];
            float qv = bf2f(qf[(size_t)j * C + c]);
            float vv = bf2f(vf[(size_t)j * C + c]);
            float t = kv + qv;
            float s = 1.f / (1.f + __expf(-t));
            acc += s * vv;
        }
        h[o] = f2bf(acc);
    }
}

// ---------------- 4: BN stats (deterministic two-stage, 256 partial blocks) ----------------
template<int C>
__global__ __launch_bounds__(256) void bn_stats_kernel(const unsigned short* __restrict__ h,
                                                       float* __restrict__ part) {
    const int LPB = 256 / C;
    int c = threadIdx.x & (C - 1);
    int sub = threadIdx.x / C;
    const int nodesPer = NNODES / 256;
    int n0 = blockIdx.x * nodesPer;
    float s = 0.f, s2 = 0.f;
    for (int i = sub; i < nodesPer; i += LPB) {
        float v = bf2f(h[(size_t)(n0 + i) * C + c]);
        s += v; s2 += v * v;
    }
    __shared__ float ls[256], ls2[256];
    ls[threadIdx.x] = s; ls2[threadIdx.x] = s2;
    __syncthreads();
    if (threadIdx.x < C) {
        #pragma unroll
        for (int l = 1; l < LPB; ++l) { s += ls[threadIdx.x + l*C]; s2 += ls2[threadIdx.x + l*C]; }
        part[(size_t)blockIdx.x * 2 * C + c]     = s;
        part[(size_t)blockIdx.x * 2 * C + C + c] = s2;
    }
}

__global__ void bn_finalize_kernel(const float* __restrict__ part,
                                   const float* __restrict__ gamma, const float* __restrict__ beta,
                                   float* __restrict__ ss, int C) {
    int c = threadIdx.x;
    if (c >= C) return;
    float s = 0.f, s2 = 0.f;
    for (int b = 0; b < 256; ++b) { s += part[(size_t)b*2*C + c]; s2 += part[(size_t)b*2*C + C + c]; }
    float m   = s / (float)NNODES;
    float var = s2 / (float)NNODES - m * m;
    float inv = rsqrtf(var + 1e-5f);
    float sc  = gamma[c] * inv;
    ss[c]     = sc;
    ss[C + c] = beta[c] - m * sc;
}

// ---------------- 5: BN+ReLU in place (layer-1 activations) ----------------
__global__ __launch_bounds__(256) void bnrelu_kernel(unsigned short* __restrict__ h,
                                                     const float* __restrict__ ss) {
    size_t i = ((size_t)blockIdx.x * blockDim.x + threadIdx.x) * 8;
    if (i >= (size_t)NNODES * 64) return;
    ushort8 v = *(const ushort8*)(h + i);
    int cbase = (int)(i & 63);
    ushort8 o;
    #pragma unroll
    for (int j = 0; j < 8; ++j) {
        int c = cbase + j;
        float f = bf2f(v[j]) * ss[c] + ss[64 + c];
        o[j] = f2bf(fmaxf(f, 0.f));
    }
    *(ushort8*)(h + i) = o;
}

// ---------------- 6: pre-build bf16 MFMA B-fragments for the 4 layer-2 weights ----------------
// slot = m*16 + kt*8 + ct ; lane l supplies col=ct*16+(l&15), k=kt*32+(l>>4)*8+e  (e=0..7)
__global__ __launch_bounds__(64) void wfrag_kernel(
    const float* __restrict__ w0, const float* __restrict__ w1,
    const float* __restrict__ w2, const float* __restrict__ w3,
    unsigned short* __restrict__ frag) {
    int m  = blockIdx.x >> 4;
    int kt = (blockIdx.x >> 3) & 1;
    int ct = blockIdx.x & 7;
    const float* w = (m == 0) ? w0 : (m == 1) ? w1 : (m == 2) ? w2 : w3;
    int l = threadIdx.x;
    int col = ct * 16 + (l & 15);
    int kbase = kt * 32 + (l >> 4) * 8;
    unsigned short* out = frag + ((size_t)blockIdx.x * 64 + l) * 8;
    #pragma unroll
    for (int e = 0; e < 8; ++e) out[e] = f2bf(w[(size_t)(kbase + e) * 128 + col]);
}

// ---------------- 7: feat2 — h1n(64) -> kf2/qf2/vf2/sk2 (128) via MFMA 16x16x32 bf16 ----------------
// A-frag uses the SAME slot->k map as wfrag, so any HW k-permutation cancels.
// C/D map (verified): col = lane&15, row = (lane>>4)*4 + reg.
__global__ __launch_bounds__(256) void feat2_kernel(
    const unsigned short* __restrict__ h1n, const unsigned short* __restrict__ frag,
    const float* __restrict__ b0, const float* __restrict__ b1,
    const float* __restrict__ b2, const float* __restrict__ b3,
    unsigned short* __restrict__ o0, unsigned short* __restrict__ o1,
    unsigned short* __restrict__ o2, unsigned short* __restrict__ o3) {
    int nt = blockIdx.x >> 3;
    int ct = blockIdx.x & 7;
    int m  = threadIdx.x >> 6;
    int l  = threadIdx.x & 63;
    const float* bm        = (m == 0) ? b0 : (m == 1) ? b1 : (m == 2) ? b2 : b3;
    unsigned short* om     = (m == 0) ? o0 : (m == 1) ? o1 : (m == 2) ? o2 : o3;
    int lr = l & 15;
    int g  = l >> 4;
    int n  = nt * 16 + lr;
    const unsigned short* ar = h1n + (size_t)n * 64 + g * 8;
    short8 a0 = *(const short8*)ar;
    short8 a1 = *(const short8*)(ar + 32);
    size_t fb0 = ((size_t)(m * 16 + 0 * 8 + ct) * 64 + l) * 8;
    size_t fb1 = ((size_t)(m * 16 + 1 * 8 + ct) * 64 + l) * 8;
    short8 w0 = *(const short8*)(frag + fb0);
    short8 w1 = *(const short8*)(frag + fb1);
    float bv = bm[ct * 16 + lr];
    floatx4 acc = {bv, bv, bv, bv};
    acc = __builtin_amdgcn_mfma_f32_16x16x32_bf16(a0, w0, acc, 0, 0, 0);
    acc = __builtin_amdgcn_mfma_f32_16x16x32_bf16(a1, w1, acc, 0, 0, 0);
    int ocol = ct * 16 + lr;
    #pragma unroll
    for (int r = 0; r < 4; ++r) {
        int orow = nt * 16 + g * 4 + r;
        om[(size_t)orow * 128 + ocol] = f2bf(acc[r]);
    }
}

// ---------------- 8: mean-pool with fused BN2+ReLU ----------------
__global__ __launch_bounds__(1024) void pool_kernel(const unsigned short* __restrict__ h2,
                                                    const float* __restrict__ ss2,
                                                    float* __restrict__ out) {
    __shared__ float red[1024];
    int g = blockIdx.x;
    int c = threadIdx.x & 127;
    int isub = threadIdx.x >> 7;  // 0..7
    float sc = ss2[c], sh = ss2[128 + c];
    float acc = 0.f;
    const unsigned short* hp = h2 + (size_t)g * NPER * 128;
    for (int i = isub; i < NPER; i += 8) {
        float v = bf2f(hp[(size_t)i * 128 + c]) * sc + sh;
        acc += fmaxf(v, 0.f);
    }
    red[threadIdx.x] = acc;
    __syncthreads();
    if (threadIdx.x < 128) {
        float s = acc;
        #pragma unroll
        for (int l = 1; l < 8; ++l) s += red[threadIdx.x + l * 128];
        out[(size_t)g * 128 + threadIdx.x] = s * (1.f / 1024.f);
    }
}

extern "C" void kernel_launch(void* const* d_in, const int* in_sizes, int n_in,
                              void* d_out, int out_size, void* d_ws, size_t ws_size,
                              hipStream_t stream) {
    const float* x   = (const float*)d_in[0];
    const float* pos = (const float*)d_in[1];
    const float* wk1 = (const float*)d_in[3];
    const float* bk1 = (const float*)d_in[4];
    const float* wq1 = (const float*)d_in[5];
    const float* bq1 = (const float*)d_in[6];
    const float* wv1 = (const float*)d_in[7];
    const float* bv1 = (const float*)d_in[8];
    const float* ws1 = (const float*)d_in[9];
    const float* bs1 = (const float*)d_in[10];
    const float* g1  = (const float*)d_in[11];
    const float* be1 = (const float*)d_in[12];
    const float* wk2 = (const float*)d_in[13];
    const float* bk2 = (const float*)d_in[14];
    const float* wq2 = (const float*)d_in[15];
    const float* bq2 = (const float*)d_in[16];
    const float* wv2 = (const float*)d_in[17];
    const float* bv2 = (const float*)d_in[18];
    const float* ws2 = (const float*)d_in[19];
    const float* bs2 = (const float*)d_in[20];
    const float* g2  = (const float*)d_in[21];
    const float* be2 = (const float*)d_in[22];
    float* out = (float*)d_out;

    const size_t SZ_F1 = (size_t)NNODES * 64 * 2;   // 16 MiB (bf16 N x 64)
    const size_t SZ_F2 = (size_t)NNODES * 128 * 2;  // 32 MiB (bf16 N x 128)

    char* ws = (char*)d_ws;
    size_t off = 0;
    auto alloc = [&](size_t b) { size_t o = off; off += (b + 255) & ~(size_t)255; return o; };

    int* idx              = (int*)(ws + alloc((size_t)NNODES * NK * 4));
    size_t o_region       = alloc(4 * SZ_F2);       // kqvs2 region; kqvs1 aliased in front
    unsigned short* kf1   = (unsigned short*)(ws + o_region);
    unsigned short* qf1   = (unsigned short*)(ws + o_region + SZ_F1);
    unsigned short* vf1   = (unsigned short*)(ws + o_region + 2 * SZ_F1);
    unsigned short* sk1   = (unsigned short*)(ws + o_region + 3 * SZ_F1);
    unsigned short* kf2   = (unsigned short*)(ws + o_region);
    unsigned short* qf2   = (unsigned short*)(ws + o_region + SZ_F2);
    unsigned short* vf2   = (unsigned short*)(ws + o_region + 2 * SZ_F2);
    unsigned short* sk2   = (unsigned short*)(ws + o_region + 3 * SZ_F2);
    unsigned short* h1    = (unsigned short*)(ws + alloc(SZ_F1));
    unsigned short* h2    = (unsigned short*)(ws + alloc(SZ_F2));
    unsigned short* frag  = (unsigned short*)(ws + alloc(64 * 64 * 8 * 2));
    float* part           = (float*)(ws + alloc(256 * 2 * 128 * 4));
    float* ss1            = (float*)(ws + alloc(2 * 64 * 4));
    float* ss2            = (float*)(ws + alloc(2 * 128 * 4));
    floatx4* p4           = (floatx4*)(ws + alloc((size_t)NNODES * 16));
    (void)ws_size; (void)in_sizes; (void)n_in; (void)out_size;

    repack_pos_kernel<<<NNODES / 256, 256, 0, stream>>>(pos, p4);
    knn_kernel<<<BGR * 2, 512, 0, stream>>>(p4, idx);
    feat1_kernel<<<1024, 256, 0, stream>>>(x, wk1, bk1, wq1, bq1, wv1, bv1, ws1, bs1,
                                           kf1, qf1, vf1, sk1);
    conv_kernel<64><<<1024, 256, 0, stream>>>(kf1, qf1, vf1, sk1, idx, h1);
    bn_stats_kernel<64><<<256, 256, 0, stream>>>(h1, part);
    bn_finalize_kernel<<<1, 64, 0, stream>>>(part, g1, be1, ss1, 64);
    bnrelu_kernel<<<(NNODES * 64 / 8) / 256, 256, 0, stream>>>(h1, ss1);
    wfrag_kernel<<<64, 64, 0, stream>>>(wk2, wq2, wv2, ws2, frag);
    feat2_kernel<<<(NNODES / 16) * 8, 256, 0, stream>>>(h1, frag, bk2, bq2, bv2, bs2,
                                                        kf2, qf2, vf2, sk2);
    conv_kernel<128><<<4096, 256, 0, stream>>>(kf2, qf2, vf2, sk2, idx, h2);
    bn_stats_kernel<128><<<256, 256, 0, stream>>>(h2, part);
    bn_finalize_kernel<<<1, 128, 0, stream>>>(part, g2, be2, ss2, 128);
    pool_kernel<<<BGR, 1024, 0, stream>>>(h2, ss2, out);
}

// Round 2
// 542.740 us; speedup vs baseline: 1.1597x; 1.1597x over previous
//
#include <hip/hip_runtime.h>
#include <hip/hip_bf16.h>

#define BGR   128
#define NPER  1024
#define NK    7
#define NNODES (BGR*NPER)

typedef __attribute__((ext_vector_type(8))) short short8;
typedef __attribute__((ext_vector_type(8))) unsigned short ushort8;
typedef __attribute__((ext_vector_type(4))) float floatx4;

static __device__ __forceinline__ float bf2f(unsigned short u) {
    unsigned int x = ((unsigned int)u) << 16;
    return __builtin_bit_cast(float, x);
}
static __device__ __forceinline__ unsigned short f2bf(float f) {
    unsigned int x = __builtin_bit_cast(unsigned int, f);
    unsigned int lsb = (x >> 16) & 1u;
    x += 0x7fffu + lsb;
    return (unsigned short)(x >> 16);
}

// ---------------- 0: repack pos into float4 ----------------
__global__ __launch_bounds__(256) void repack_pos_kernel(const float* __restrict__ pos,
                                                         floatx4* __restrict__ p4) {
    int i = blockIdx.x * blockDim.x + threadIdx.x;
    if (i < NNODES) {
        floatx4 v;
        v.x = pos[(size_t)i*3+0]; v.y = pos[(size_t)i*3+1]; v.z = pos[(size_t)i*3+2]; v.w = 0.f;
        p4[i] = v;
    }
}

// ---------------- 1: per-graph brute-force kNN, LDS-staged ----------------
// 4 blocks/graph x 256 threads; all 1024 graph positions in LDS; unroll-8 j loop
// with a single rare-path gate (min-of-8 < current 7th best).
__global__ __launch_bounds__(256) void knn_kernel(const floatx4* __restrict__ p4,
                                                  int* __restrict__ idx) {
    __shared__ floatx4 sp[NPER];
    int g = blockIdx.x >> 2;
    int i_local = ((blockIdx.x & 3) << 8) + threadIdx.x;
    int base = g * NPER;
    const floatx4* pg = p4 + base;
    for (int j = threadIdx.x; j < NPER; j += 256) sp[j] = pg[j];
    __syncthreads();
    floatx4 me = sp[i_local];
    float b0=3e38f,b1=3e38f,b2=3e38f,b3=3e38f,b4=3e38f,b5=3e38f,b6=3e38f;
    int   i0=0,i1=0,i2=0,i3=0,i4=0,i5=0,i6=0;
    for (int j0 = 0; j0 < NPER; j0 += 8) {
        float dd[8];
        #pragma unroll
        for (int u = 0; u < 8; ++u) {
            floatx4 q = sp[j0 + u];
            float dx = me.x-q.x, dy = me.y-q.y, dz = me.z-q.z;
            float d = dx*dx + dy*dy + dz*dz;
            dd[u] = (j0 + u == i_local) ? 3e38f : d;
        }
        float m01 = fminf(dd[0],dd[1]), m23 = fminf(dd[2],dd[3]);
        float m45 = fminf(dd[4],dd[5]), m67 = fminf(dd[6],dd[7]);
        float mall = fminf(fminf(m01,m23), fminf(m45,m67));
        if (mall < b6) {
            #pragma unroll
            for (int u = 0; u < 8; ++u) {
                float t = dd[u]; int ti = j0 + u;
                if (t < b6) {
                    #define BUB(bb,ii) { bool c = t < bb; float tf = bb; int tii = ii; \
                                         bb = c ? t : bb; ii = c ? ti : ii; t = c ? tf : t; ti = c ? tii : ti; }
                    BUB(b0,i0) BUB(b1,i1) BUB(b2,i2) BUB(b3,i3) BUB(b4,i4) BUB(b5,i5) BUB(b6,i6)
                    #undef BUB
                }
            }
        }
    }
    int* op = idx + (size_t)(base + i_local) * NK;
    op[0]=base+i0; op[1]=base+i1; op[2]=base+i2; op[3]=base+i3;
    op[4]=base+i4; op[5]=base+i5; op[6]=base+i6;
}

// ---------------- 2: feat1 — x(16) -> kf/qf/vf/sk (64), W in registers ----------------
__global__ __launch_bounds__(256) void feat1_kernel(
    const float* __restrict__ x,
    const float* __restrict__ wk, const float* __restrict__ bk,
    const float* __restrict__ wq, const float* __restrict__ bq,
    const float* __restrict__ wv, const float* __restrict__ bv,
    const float* __restrict__ wsm, const float* __restrict__ bs,
    unsigned short* __restrict__ kf, unsigned short* __restrict__ qf,
    unsigned short* __restrict__ vf, unsigned short* __restrict__ sk) {
    int c = threadIdx.x & 63;
    float Wk[16], Wq[16], Wv[16], Ws[16];
    #pragma unroll
    for (int k = 0; k < 16; ++k) {
        Wk[k] = wk[k*64+c]; Wq[k] = wq[k*64+c]; Wv[k] = wv[k*64+c]; Ws[k] = wsm[k*64+c];
    }
    float Bk = bk[c], Bq = bq[c], Bv = bv[c], Bs = bs[c];
    int wave = blockIdx.x * (blockDim.x >> 6) + (threadIdx.x >> 6);
    int nw   = gridDim.x * (blockDim.x >> 6);
    for (int n = wave; n < NNODES; n += nw) {
        const float* xr = x + (size_t)n * 16;
        float ak = Bk, aq = Bq, av = Bv, as = Bs;
        #pragma unroll
        for (int k = 0; k < 16; ++k) {
            float xv = xr[k];
            ak += xv * Wk[k]; aq += xv * Wq[k]; av += xv * Wv[k]; as += xv * Ws[k];
        }
        size_t o = (size_t)n * 64 + c;
        kf[o] = f2bf(ak); qf[o] = f2bf(aq); vf[o] = f2bf(av); sk[o] = f2bf(as);
    }
}

// ---------------- 3: gated conv — 32 contiguous nodes per block (L2 locality) ----------------
template<int C>
__global__ __launch_bounds__(256) void conv_kernel(
    const unsigned short* __restrict__ kf, const unsigned short* __restrict__ qf,
    const unsigned short* __restrict__ vf, const unsigned short* __restrict__ sk,
    const int* __restrict__ idx, unsigned short* __restrict__ h) {
    const int NPB = 256 / C;               // nodes processed per pass
    int c   = threadIdx.x & (C - 1);
    int sub = threadIdx.x / C;
    int n0  = blockIdx.x * 32;
    for (int i = sub; i < 32; i += NPB) {
        int n = n0 + i;
        const int* nb = idx + (size_t)n * NK;
        size_t o = (size_t)n * C + c;
        float kv  = bf2f(kf[o]);
        float acc = bf2f(sk[o]);
        #pragma unroll
        for (int k = 0; k < NK; ++k) {
            int j = nb[k];
            float qv = bf2f(qf[(size_t)j * C + c]);
            float vv = bf2f(vf[(size_t)j * C + c]);
            float t = kv + qv;
            float s = 1.f / (1.f + __expf(-t));
            acc += s * vv;
        }
        h[o] = f2bf(acc);
    }
}

// ---------------- 4: BN stats (deterministic two-stage) ----------------
template<int C>
__global__ __launch_bounds__(256) void bn_stats_kernel(const unsigned short* __restrict__ h,
                                                       float* __restrict__ part) {
    const int LPB = 256 / C;
    int c = threadIdx.x & (C - 1);
    int sub = threadIdx.x / C;
    const int nodesPer = NNODES / 256;
    int n0 = blockIdx.x * nodesPer;
    float s = 0.f, s2 = 0.f;
    for (int i = sub; i < nodesPer; i += LPB) {
        float v = bf2f(h[(size_t)(n0 + i) * C + c]);
        s += v; s2 += v * v;
    }
    __shared__ float ls[256], ls2[256];
    ls[threadIdx.x] = s; ls2[threadIdx.x] = s2;
    __syncthreads();
    if (threadIdx.x < C) {
        #pragma unroll
        for (int l = 1; l < LPB; ++l) { s += ls[threadIdx.x + l*C]; s2 += ls2[threadIdx.x + l*C]; }
        part[(size_t)blockIdx.x * 2 * C + c]     = s;
        part[(size_t)blockIdx.x * 2 * C + C + c] = s2;
    }
}

__global__ void bn_finalize_kernel(const float* __restrict__ part,
                                   const float* __restrict__ gamma, const float* __restrict__ beta,
                                   float* __restrict__ ss, int C) {
    int c = threadIdx.x;
    if (c >= C) return;
    float s = 0.f, s2 = 0.f;
    for (int b = 0; b < 256; ++b) { s += part[(size_t)b*2*C + c]; s2 += part[(size_t)b*2*C + C + c]; }
    float m   = s / (float)NNODES;
    float var = s2 / (float)NNODES - m * m;
    float inv = rsqrtf(var + 1e-5f);
    float sc  = gamma[c] * inv;
    ss[c]     = sc;
    ss[C + c] = beta[c] - m * sc;
}

// ---------------- 6: bf16 MFMA B-fragments for the 4 layer-2 weights ----------------
// slot = m*16 + kt*8 + ct ; lane l supplies col=ct*16+(l&15), k=kt*32+(l>>4)*8+e
__global__ __launch_bounds__(64) void wfrag_kernel(
    const float* __restrict__ w0, const float* __restrict__ w1,
    const float* __restrict__ w2, const float* __restrict__ w3,
    unsigned short* __restrict__ frag) {
    int m  = blockIdx.x >> 4;
    int kt = (blockIdx.x >> 3) & 1;
    int ct = blockIdx.x & 7;
    const float* w = (m == 0) ? w0 : (m == 1) ? w1 : (m == 2) ? w2 : w3;
    int l = threadIdx.x;
    int col = ct * 16 + (l & 15);
    int kbase = kt * 32 + (l >> 4) * 8;
    unsigned short* out = frag + ((size_t)blockIdx.x * 64 + l) * 8;
    #pragma unroll
    for (int e = 0; e < 8; ++e) out[e] = f2bf(w[(size_t)(kbase + e) * 128 + col]);
}

// ---------------- 7: feat2 — fused BN1+ReLU on load, all 8 col-tiles per block ----------------
// A-frag uses the SAME slot->k map as wfrag (k-permutation cancels).
// C/D map: col = lane&15, row = (lane>>4)*4 + reg.
__global__ __launch_bounds__(256) void feat2_kernel(
    const unsigned short* __restrict__ h1n, const unsigned short* __restrict__ frag,
    const float* __restrict__ ss1,
    const float* __restrict__ b0, const float* __restrict__ b1,
    const float* __restrict__ b2, const float* __restrict__ b3,
    unsigned short* __restrict__ o0, unsigned short* __restrict__ o1,
    unsigned short* __restrict__ o2, unsigned short* __restrict__ o3) {
    int nt = blockIdx.x;
    int m  = threadIdx.x >> 6;
    int l  = threadIdx.x & 63;
    const float* bm        = (m == 0) ? b0 : (m == 1) ? b1 : (m == 2) ? b2 : b3;
    unsigned short* om     = (m == 0) ? o0 : (m == 1) ? o1 : (m == 2) ? o2 : o3;
    int lr = l & 15;
    int gq = l >> 4;
    int n  = nt * 16 + lr;
    const unsigned short* ar = h1n + (size_t)n * 64 + gq * 8;
    short8 a0r = *(const short8*)ar;
    short8 a1r = *(const short8*)(ar + 32);
    short8 a0, a1;
    #pragma unroll
    for (int e = 0; e < 8; ++e) {
        int c0 = gq * 8 + e;
        float f0 = bf2f((unsigned short)a0r[e]) * ss1[c0] + ss1[64 + c0];
        a0[e] = (short)f2bf(fmaxf(f0, 0.f));
        int c1 = 32 + gq * 8 + e;
        float f1 = bf2f((unsigned short)a1r[e]) * ss1[c1] + ss1[64 + c1];
        a1[e] = (short)f2bf(fmaxf(f1, 0.f));
    }
    #pragma unroll
    for (int ct = 0; ct < 8; ++ct) {
        size_t fb0 = ((size_t)(m * 16 + ct)     * 64 + l) * 8;
        size_t fb1 = ((size_t)(m * 16 + 8 + ct) * 64 + l) * 8;
        short8 w0 = *(const short8*)(frag + fb0);
        short8 w1 = *(const short8*)(frag + fb1);
        float bv = bm[ct * 16 + lr];
        floatx4 acc = {bv, bv, bv, bv};
        acc = __builtin_amdgcn_mfma_f32_16x16x32_bf16(a0, w0, acc, 0, 0, 0);
        acc = __builtin_amdgcn_mfma_f32_16x16x32_bf16(a1, w1, acc, 0, 0, 0);
        int ocol = ct * 16 + lr;
        #pragma unroll
        for (int r = 0; r < 4; ++r) {
            int orow = nt * 16 + gq * 4 + r;
            om[(size_t)orow * 128 + ocol] = f2bf(acc[r]);
        }
    }
}

// ---------------- 8: mean-pool with fused BN2+ReLU, two-stage ----------------
__global__ __launch_bounds__(256) void pool_partial_kernel(const unsigned short* __restrict__ h2,
                                                           const float* __restrict__ ss2,
                                                           float* __restrict__ part) {
    int g = blockIdx.x >> 2;
    int q = blockIdx.x & 3;
    int c = threadIdx.x & 127;
    int isub = threadIdx.x >> 7;  // 0..1
    float sc = ss2[c], sh = ss2[128 + c];
    float acc = 0.f;
    const unsigned short* hp = h2 + ((size_t)g * NPER + q * 256) * 128;
    for (int i = isub; i < 256; i += 2)
        acc += fmaxf(bf2f(hp[(size_t)i * 128 + c]) * sc + sh, 0.f);
    __shared__ float red[256];
    red[threadIdx.x] = acc;
    __syncthreads();
    if (threadIdx.x < 128)
        part[(size_t)blockIdx.x * 128 + c] = acc + red[threadIdx.x + 128];
}

__global__ void pool_final_kernel(const float* __restrict__ part, float* __restrict__ out) {
    int g = blockIdx.x, c = threadIdx.x;
    float s = part[(size_t)(g*4+0)*128+c] + part[(size_t)(g*4+1)*128+c]
            + part[(size_t)(g*4+2)*128+c] + part[(size_t)(g*4+3)*128+c];
    out[(size_t)g * 128 + c] = s * (1.f / 1024.f);
}

extern "C" void kernel_launch(void* const* d_in, const int* in_sizes, int n_in,
                              void* d_out, int out_size, void* d_ws, size_t ws_size,
                              hipStream_t stream) {
    const float* x   = (const float*)d_in[0];
    const float* pos = (const float*)d_in[1];
    const float* wk1 = (const float*)d_in[3];
    const float* bk1 = (const float*)d_in[4];
    const float* wq1 = (const float*)d_in[5];
    const float* bq1 = (const float*)d_in[6];
    const float* wv1 = (const float*)d_in[7];
    const float* bv1 = (const float*)d_in[8];
    const float* ws1 = (const float*)d_in[9];
    const float* bs1 = (const float*)d_in[10];
    const float* g1  = (const float*)d_in[11];
    const float* be1 = (const float*)d_in[12];
    const float* wk2 = (const float*)d_in[13];
    const float* bk2 = (const float*)d_in[14];
    const float* wq2 = (const float*)d_in[15];
    const float* bq2 = (const float*)d_in[16];
    const float* wv2 = (const float*)d_in[17];
    const float* bv2 = (const float*)d_in[18];
    const float* ws2 = (const float*)d_in[19];
    const float* bs2 = (const float*)d_in[20];
    const float* g2  = (const float*)d_in[21];
    const float* be2 = (const float*)d_in[22];
    float* out = (float*)d_out;

    const size_t SZ_F1 = (size_t)NNODES * 64 * 2;   // 16 MiB
    const size_t SZ_F2 = (size_t)NNODES * 128 * 2;  // 32 MiB

    char* ws = (char*)d_ws;
    size_t off = 0;
    auto alloc = [&](size_t b) { size_t o = off; off += (b + 255) & ~(size_t)255; return o; };

    int* idx              = (int*)(ws + alloc((size_t)NNODES * NK * 4));
    size_t o_region       = alloc(4 * SZ_F2);       // kqvs2 region; kqvs1 aliased in front
    unsigned short* kf1   = (unsigned short*)(ws + o_region);
    unsigned short* qf1   = (unsigned short*)(ws + o_region + SZ_F1);
    unsigned short* vf1   = (unsigned short*)(ws + o_region + 2 * SZ_F1);
    unsigned short* sk1   = (unsigned short*)(ws + o_region + 3 * SZ_F1);
    unsigned short* kf2   = (unsigned short*)(ws + o_region);
    unsigned short* qf2   = (unsigned short*)(ws + o_region + SZ_F2);
    unsigned short* vf2   = (unsigned short*)(ws + o_region + 2 * SZ_F2);
    unsigned short* sk2   = (unsigned short*)(ws + o_region + 3 * SZ_F2);
    unsigned short* h1    = (unsigned short*)(ws + alloc(SZ_F1));
    unsigned short* h2    = (unsigned short*)(ws + alloc(SZ_F2));
    unsigned short* frag  = (unsigned short*)(ws + alloc(64 * 64 * 8 * 2));
    float* part           = (float*)(ws + alloc(512 * 128 * 4));
    float* ss1            = (float*)(ws + alloc(2 * 64 * 4));
    float* ss2            = (float*)(ws + alloc(2 * 128 * 4));
    floatx4* p4           = (floatx4*)(ws + alloc((size_t)NNODES * 16));
    (void)ws_size; (void)in_sizes; (void)n_in; (void)out_size;

    repack_pos_kernel<<<NNODES / 256, 256, 0, stream>>>(pos, p4);
    knn_kernel<<<BGR * 4, 256, 0, stream>>>(p4, idx);
    feat1_kernel<<<1024, 256, 0, stream>>>(x, wk1, bk1, wq1, bq1, wv1, bv1, ws1, bs1,
                                           kf1, qf1, vf1, sk1);
    conv_kernel<64><<<NNODES / 32, 256, 0, stream>>>(kf1, qf1, vf1, sk1, idx, h1);
    bn_stats_kernel<64><<<256, 256, 0, stream>>>(h1, part);
    bn_finalize_kernel<<<1, 64, 0, stream>>>(part, g1, be1, ss1, 64);
    wfrag_kernel<<<64, 64, 0, stream>>>(wk2, wq2, wv2, ws2, frag);
    feat2_kernel<<<NNODES / 16, 256, 0, stream>>>(h1, frag, ss1, bk2, bq2, bv2, bs2,
                                                  kf2, qf2, vf2, sk2);
    conv_kernel<128><<<NNODES / 32, 256, 0, stream>>>(kf2, qf2, vf2, sk2, idx, h2);
    bn_stats_kernel<128><<<256, 256, 0, stream>>>(h2, part);
    bn_finalize_kernel<<<1, 128, 0, stream>>>(part, g2, be2, ss2, 128);
    pool_partial_kernel<<<BGR * 4, 256, 0, stream>>>(h2, ss2, part);
    pool_final_kernel<<<BGR, 128, 0, stream>>>(part, out);
}